// Round 3
// baseline (4136.876 us; speedup 1.0000x reference)
//
#include <hip/hip_runtime.h>
#include <math.h>

#define NN 100000
#define NE 3200000
#define D 64
#define H 4096
#define H3 12288
#define NB2 782          // (NN+127)/128 buckets of 128 dst nodes
#define NTILES 6250      // NN/16 node tiles for MFMA gemm

typedef __attribute__((ext_vector_type(8))) short short8;
typedef __attribute__((ext_vector_type(4))) float f32x4;

// bf16 helpers (round-to-nearest-even)
__device__ inline unsigned short f2bf(float f) {
    unsigned u = __float_as_uint(f);
    unsigned r = (u + 0x7FFFu + ((u >> 16) & 1u)) >> 16;
    return (unsigned short)r;
}
__device__ inline float bf2f(unsigned short h) {
    return __uint_as_float(((unsigned)h) << 16);
}

// ---------------- degree counting ----------------
__global__ __launch_bounds__(256) void deg_kernel(const int* __restrict__ src,
                                                  const int* __restrict__ dst,
                                                  int* __restrict__ outcnt,
                                                  int* __restrict__ incnt) {
    int e = blockIdx.x * 256 + threadIdx.x;
    if (e < NE) {
        atomicAdd(&outcnt[src[e]], 1);
        atomicAdd(&incnt[dst[e]], 1);
    }
}

__global__ __launch_bounds__(256) void norm_kernel(const int* __restrict__ outcnt,
                                                   const int* __restrict__ incnt,
                                                   float* __restrict__ outn,
                                                   float* __restrict__ innorm) {
    int i = blockIdx.x * 256 + threadIdx.x;
    if (i < NN) {
        outn[i]   = rsqrtf(fmaxf((float)outcnt[i], 1.0f));
        innorm[i] = rsqrtf(fmaxf((float)incnt[i],  1.0f));
    }
}

// ---------------- bucket counts: one wave per bucket ----------------
__global__ __launch_bounds__(256) void bcnt_kernel(const int* __restrict__ incnt,
                                                   int* __restrict__ bcnt) {
    int gid = blockIdx.x * 256 + threadIdx.x;
    int w = gid >> 6, lane = gid & 63;
    if (w >= NB2) return;
    int base = w << 7;
    int s = 0;
    int i0 = base + lane, i1 = base + lane + 64;
    if (i0 < NN) s += incnt[i0];
    if (i1 < NN) s += incnt[i1];
    for (int off = 32; off; off >>= 1) s += __shfl_down(s, off);
    if (lane == 0) bcnt[w] = s;
}

// ---------------- exclusive scan of 782 bucket counts (single block) -------
__global__ __launch_bounds__(1024) void bscan_kernel(const int* __restrict__ bcnt,
                                                     int* __restrict__ bptr,
                                                     int* __restrict__ cursor) {
    __shared__ int s[1024];
    int t = threadIdx.x;
    int c = (t < NB2) ? bcnt[t] : 0;
    s[t] = c;
    __syncthreads();
    for (int off = 1; off < 1024; off <<= 1) {
        int v = (t >= off) ? s[t - off] : 0;
        __syncthreads();
        s[t] += v;
        __syncthreads();
    }
    if (t < NB2) {
        int excl = s[t] - c;
        bptr[t] = excl;
        cursor[t] = excl;
    }
    if (t == 0) bptr[NB2] = NE;
}

// ---------------- bucket fill: packed = src | (dstLocal<<20) ----------------
__global__ __launch_bounds__(256) void bucket_fill(const int* __restrict__ src,
                                                   const int* __restrict__ dst,
                                                   int* __restrict__ cursor,
                                                   int* __restrict__ packed) {
    int e = blockIdx.x * 256 + threadIdx.x;
    if (e < NE) {
        int d = dst[e];
        int b = d >> 7;
        int pos = atomicAdd(&cursor[b], 1);
        packed[pos] = src[e] | ((d & 127) << 20);
    }
}

// ---------------- GRU: fused matvec for both cells ----------------
__global__ __launch_bounds__(256) void gru_matvec(
    const float* __restrict__ Wih, const float* __restrict__ Whh,
    const float* __restrict__ bih, const float* __restrict__ bhh,
    const float* __restrict__ pg1, const float* __restrict__ pg2,
    const float* __restrict__ g1w, const float* __restrict__ g2w,
    float* __restrict__ gi1, float* __restrict__ gh1,
    float* __restrict__ gi2, float* __restrict__ gh2) {
    int r = blockIdx.x;
    int tid = threadIdx.x;
    const float4* wi = (const float4*)(Wih + (size_t)r * H);
    const float4* wh = (const float4*)(Whh + (size_t)r * H);
    const float4* x1 = (const float4*)pg1;
    const float4* x2 = (const float4*)pg2;
    const float4* h1 = (const float4*)g1w;
    const float4* h2 = (const float4*)g2w;
    float a0 = 0.f, a1 = 0.f, a2 = 0.f, a3 = 0.f;
    for (int k = tid; k < H / 4; k += 256) {
        float4 wiv = wi[k];
        float4 whv = wh[k];
        float4 v1 = x1[k], v2 = x2[k], u1 = h1[k], u2 = h2[k];
        a0 += wiv.x * v1.x + wiv.y * v1.y + wiv.z * v1.z + wiv.w * v1.w;
        a1 += whv.x * u1.x + whv.y * u1.y + whv.z * u1.z + whv.w * u1.w;
        a2 += wiv.x * v2.x + wiv.y * v2.y + wiv.z * v2.z + wiv.w * v2.w;
        a3 += whv.x * u2.x + whv.y * u2.y + whv.z * u2.z + whv.w * u2.w;
    }
    for (int off = 32; off; off >>= 1) {
        a0 += __shfl_down(a0, off);
        a1 += __shfl_down(a1, off);
        a2 += __shfl_down(a2, off);
        a3 += __shfl_down(a3, off);
    }
    __shared__ float red[4][4];
    int wv = tid >> 6;
    if ((tid & 63) == 0) {
        red[wv][0] = a0; red[wv][1] = a1; red[wv][2] = a2; red[wv][3] = a3;
    }
    __syncthreads();
    if (tid < 4) {
        float s = red[0][tid] + red[1][tid] + red[2][tid] + red[3][tid];
        if (tid == 0)      gi1[r] = s + bih[r];
        else if (tid == 1) gh1[r] = s + bhh[r];
        else if (tid == 2) gi2[r] = s + bih[r];
        else               gh2[r] = s + bhh[r];
    }
}

__global__ __launch_bounds__(256) void gru_combine(
    const float* __restrict__ gi1, const float* __restrict__ gh1,
    const float* __restrict__ gi2, const float* __restrict__ gh2,
    const float* __restrict__ g1w, const float* __restrict__ g2w,
    float* __restrict__ w1, float* __restrict__ w2) {
    int gid = blockIdx.x * 256 + threadIdx.x;
    if (gid >= 2 * H) return;
    int c = gid >> 12;
    int j = gid & (H - 1);
    const float* gi = c ? gi2 : gi1;
    const float* gh = c ? gh2 : gh1;
    float hprev = c ? g2w[j] : g1w[j];
    float r = 1.f / (1.f + expf(-(gi[j] + gh[j])));
    float z = 1.f / (1.f + expf(-(gi[H + j] + gh[H + j])));
    float n = tanhf(gi[2 * H + j] + r * gh[2 * H + j]);
    float w = (1.f - z) * n + z * hprev;
    (c ? w2 : w1)[j] = w;
}

// ---------------- bucketed aggregation with LDS accumulators ----------------
// one block per bucket of 128 dst nodes; lane j owns column j.
// agg_out[node] = innorm[node] * sum_{e: dst=node} x[src]* (escale ? escale[src] : 1)
__global__ __launch_bounds__(256) void agg_kernel(
    const int* __restrict__ bptr, const int* __restrict__ packed,
    const float* __restrict__ x, const float* __restrict__ escale,
    const float* __restrict__ innorm, float* __restrict__ agg_out) {
    __shared__ float acc[128 * D];  // 32 KB
    int tid = threadIdx.x;
    for (int i = tid * 4; i < 128 * D; i += 1024) {
        *(float4*)&acc[i] = make_float4(0.f, 0.f, 0.f, 0.f);
    }
    __syncthreads();

    int b = blockIdx.x;
    int begin = bptr[b], end = bptr[b + 1];
    int len = end - begin;
    int wave = tid >> 6, lane = tid & 63;
    int e  = begin + (len * wave) / 4;
    int we = begin + (len * (wave + 1)) / 4;

    if (escale) {
        for (; e + 4 <= we; e += 4) {
            int p0 = packed[e], p1 = packed[e + 1], p2 = packed[e + 2], p3 = packed[e + 3];
            int s0 = p0 & 0xFFFFF, s1 = p1 & 0xFFFFF, s2 = p2 & 0xFFFFF, s3 = p3 & 0xFFFFF;
            float v0 = x[(size_t)s0 * D + lane] * escale[s0];
            float v1 = x[(size_t)s1 * D + lane] * escale[s1];
            float v2 = x[(size_t)s2 * D + lane] * escale[s2];
            float v3 = x[(size_t)s3 * D + lane] * escale[s3];
            atomicAdd(&acc[(p0 >> 20) * D + lane], v0);
            atomicAdd(&acc[(p1 >> 20) * D + lane], v1);
            atomicAdd(&acc[(p2 >> 20) * D + lane], v2);
            atomicAdd(&acc[(p3 >> 20) * D + lane], v3);
        }
        for (; e < we; ++e) {
            int p = packed[e];
            int s = p & 0xFFFFF;
            atomicAdd(&acc[(p >> 20) * D + lane], x[(size_t)s * D + lane] * escale[s]);
        }
    } else {
        for (; e + 4 <= we; e += 4) {
            int p0 = packed[e], p1 = packed[e + 1], p2 = packed[e + 2], p3 = packed[e + 3];
            int s0 = p0 & 0xFFFFF, s1 = p1 & 0xFFFFF, s2 = p2 & 0xFFFFF, s3 = p3 & 0xFFFFF;
            float v0 = x[(size_t)s0 * D + lane];
            float v1 = x[(size_t)s1 * D + lane];
            float v2 = x[(size_t)s2 * D + lane];
            float v3 = x[(size_t)s3 * D + lane];
            atomicAdd(&acc[(p0 >> 20) * D + lane], v0);
            atomicAdd(&acc[(p1 >> 20) * D + lane], v1);
            atomicAdd(&acc[(p2 >> 20) * D + lane], v2);
            atomicAdd(&acc[(p3 >> 20) * D + lane], v3);
        }
        for (; e < we; ++e) {
            int p = packed[e];
            atomicAdd(&acc[(p >> 20) * D + lane], x[(size_t)(p & 0xFFFFF) * D + lane]);
        }
    }
    __syncthreads();

    // epilogue: scale rows by innorm, stream out coalesced
    int base_node = b << 7;
    int nodes = min(128, NN - base_node);
    int total = nodes * D;
    for (int idx = tid * 4; idx < total; idx += 1024) {
        float4 v = *(float4*)&acc[idx];
        float inv = innorm[base_node + (idx >> 6)];
        v.x *= inv; v.y *= inv; v.z *= inv; v.w *= inv;
        *(float4*)&agg_out[(size_t)base_node * D + idx] = v;
    }
}

// ---------------- split-bf16 MFMA GEMM: out = epilogue(A @ W + bias) --------
// mode 1: out = relu(A@W + b) * outn   (layer 1, writes pre-scaled h1)
// mode 0: out = A@W + b                (layer 2, final)
__global__ __launch_bounds__(256) void gemm_mfma(
    const float* __restrict__ A, const float* __restrict__ W,
    const float* __restrict__ bias, const float* __restrict__ outn,
    float* __restrict__ out, int mode) {
    __shared__ unsigned int wlds[D * 65];  // (lo<<16)|hi per element, stride 65
    int tid = threadIdx.x;
    for (int i = tid; i < D * D; i += 256) {
        float f = W[i];
        unsigned short hi = f2bf(f);
        unsigned short lo = f2bf(f - bf2f(hi));
        wlds[(i >> 6) * 65 + (i & 63)] = (((unsigned)lo) << 16) | hi;
    }
    __syncthreads();

    int tile = blockIdx.x * 4 + (tid >> 6);
    if (tile >= NTILES) return;
    int lane = tid & 63;
    int m = lane & 15, q = lane >> 4;
    int row0 = tile * 16;

    // A fragments: 2 k-tiles, hi+lo
    short8 ah[2], al[2];
#pragma unroll
    for (int kt = 0; kt < 2; ++kt) {
        size_t base = (size_t)(row0 + m) * D + kt * 32 + q * 8;
        float4 a0 = *(const float4*)(A + base);
        float4 a1 = *(const float4*)(A + base + 4);
        float av[8] = {a0.x, a0.y, a0.z, a0.w, a1.x, a1.y, a1.z, a1.w};
#pragma unroll
        for (int j = 0; j < 8; ++j) {
            unsigned short hi = f2bf(av[j]);
            unsigned short lo = f2bf(av[j] - bf2f(hi));
            ah[kt][j] = (short)hi;
            al[kt][j] = (short)lo;
        }
    }

    f32x4 c[4];
#pragma unroll
    for (int ct = 0; ct < 4; ++ct) c[ct] = (f32x4){0.f, 0.f, 0.f, 0.f};

#pragma unroll
    for (int ct = 0; ct < 4; ++ct) {
#pragma unroll
        for (int kt = 0; kt < 2; ++kt) {
            short8 bh, bl;
#pragma unroll
            for (int j = 0; j < 8; ++j) {
                unsigned int v = wlds[(kt * 32 + q * 8 + j) * 65 + ct * 16 + m];
                bh[j] = (short)(v & 0xFFFF);
                bl[j] = (short)(v >> 16);
            }
            c[ct] = __builtin_amdgcn_mfma_f32_16x16x32_bf16(ah[kt], bh, c[ct], 0, 0, 0);
            c[ct] = __builtin_amdgcn_mfma_f32_16x16x32_bf16(ah[kt], bl, c[ct], 0, 0, 0);
            c[ct] = __builtin_amdgcn_mfma_f32_16x16x32_bf16(al[kt], bh, c[ct], 0, 0, 0);
        }
    }

    // epilogue: C/D layout col=lane&15, row=(lane>>4)*4+reg (m89-verified)
#pragma unroll
    for (int ct = 0; ct < 4; ++ct) {
        int col = ct * 16 + m;
        float bv = bias[col];
#pragma unroll
        for (int r = 0; r < 4; ++r) {
            int row = row0 + q * 4 + r;
            float v = c[ct][r] + bv;
            if (mode) v = fmaxf(v, 0.f) * outn[row];
            out[(size_t)row * D + col] = v;
        }
    }
}

extern "C" void kernel_launch(void* const* d_in, const int* in_sizes, int n_in,
                              void* d_out, int out_size, void* d_ws, size_t ws_size,
                              hipStream_t stream) {
    const float* x0   = (const float*)d_in[0];
    const float* gc1w = (const float*)d_in[1];
    const float* gc2w = (const float*)d_in[2];
    const float* gc1b = (const float*)d_in[3];
    const float* gc2b = (const float*)d_in[4];
    const float* pg1  = (const float*)d_in[5];
    const float* pg2  = (const float*)d_in[6];
    const float* Wih  = (const float*)d_in[7];
    const float* Whh  = (const float*)d_in[8];
    const float* bih  = (const float*)d_in[9];
    const float* bhh  = (const float*)d_in[10];
    const int*   src  = (const int*)d_in[11];
    const int*   dst  = (const int*)d_in[12];
    float* out = (float*)d_out;
    float* ws  = (float*)d_ws;

    // workspace layout (float offsets), peak 10.1M floats = 40.4 MB
    float* outn   = ws;                      // NN
    float* innorm = ws + 100000;             // NN
    int* outcnt = (int*)(ws + 200000);       // NN
    int* incnt  = (int*)(ws + 300000);       // NN
    int* bptr   = (int*)(ws + 400000);       // NB2+1
    int* cursor = (int*)(ws + 401000);       // NB2
    int* bcnt   = (int*)(ws + 402000);       // NB2
    float* w1 = ws + 403000;                 // H
    float* w2 = w1 + H;                      // H
    float* gi1 = ws + 420000;                // 3H each
    float* gh1 = gi1 + H3;
    float* gi2 = gh1 + H3;
    float* gh2 = gi2 + H3;                   // ends at 469152
    int* packed = (int*)(ws + 500000);       // NE
    float* aggs = ws + 3700000;              // NN*D -> ends 10.1M

    // degrees + norms
    hipMemsetAsync(outcnt, 0, (size_t)2 * NN * sizeof(int), stream);
    deg_kernel<<<(NE + 255) / 256, 256, 0, stream>>>(src, dst, outcnt, incnt);
    norm_kernel<<<(NN + 255) / 256, 256, 0, stream>>>(outcnt, incnt, outn, innorm);

    // bucket offsets + fill
    bcnt_kernel<<<(NB2 * 64 + 255) / 256, 256, 0, stream>>>(incnt, bcnt);
    bscan_kernel<<<1, 1024, 0, stream>>>(bcnt, bptr, cursor);
    bucket_fill<<<(NE + 255) / 256, 256, 0, stream>>>(src, dst, cursor, packed);

    // GRU weight evolution
    gru_matvec<<<H3, 256, 0, stream>>>(Wih, Whh, bih, bhh, pg1, pg2, gc1w, gc2w,
                                       gi1, gh1, gi2, gh2);
    gru_combine<<<(2 * H + 255) / 256, 256, 0, stream>>>(gi1, gh1, gi2, gh2,
                                                         gc1w, gc2w, w1, w2);

    // layer 1: agg (x0 * outn[src]) -> aggs;  h1s = relu(aggs@w1+b1)*outn -> d_out
    agg_kernel<<<NB2, 256, 0, stream>>>(bptr, packed, x0, outn, innorm, aggs);
    gemm_mfma<<<(NTILES + 3) / 4, 256, 0, stream>>>(aggs, w1, gc1b, outn, out, 1);

    // layer 2: agg (h1s, pre-scaled) -> aggs;  out = aggs@w2+b2
    agg_kernel<<<NB2, 256, 0, stream>>>(bptr, packed, out, nullptr, innorm, aggs);
    gemm_mfma<<<(NTILES + 3) / 4, 256, 0, stream>>>(aggs, w2, gc2b, nullptr, out, 0);
}